// Round 5
// baseline (116.154 us; speedup 1.0000x reference)
//
#include <hip/hip_runtime.h>

#define N_IMG 8
#define CIN   64
#define H     112
#define W     112
#define P     (H * W)          // 12544
#define PG    (P / 4)          // 3136 float4 pixel-groups
#define D     576              // CIN * 3 * 3
#define COUT  64
#define MEM   1025             // memo table size
#define RB    8                // output rows per band
#define NBAND (H / RB)         // 14
#define HALO_ROWS (RB + 2)     // 10
#define HALO_PIX  (HALO_ROWS * W)  // 1120
#define HALO_F4   (HALO_PIX / 4)   // 280
#define OUT_PIX   (RB * W)         // 896
#define NB_BINS (N_IMG * NBAND)    // 112 band blocks
#define NB_WT   16                 // weight-transpose blocks

// ---------------------------------------------------------------------------
// K1: fused channel sum (f64, float4 loads) + 3x3 zero-padded box sum +
//     quantize + per-block LDS dedup + DENSE per-band table write (no global
//     atomics, no separate sentinel-init dispatch).
//     Blocks 0..111: (image, row-band). Blocks 112..127: weight transpose.
__global__ __launch_bounds__(256) void fused_bins_kernel(
    const float* __restrict__ fmap, const float* __restrict__ weight,
    float* __restrict__ wT, int* __restrict__ bins,
    int* __restrict__ first_band) {
  __shared__ double Tl[HALO_PIX];      // 8960 B: channel sums, 10 halo rows
  __shared__ int lfirst[MEM];          // 4100 B: per-block dedup table
  const int t = threadIdx.x;
  const int g = blockIdx.x;

  if (g >= NB_BINS) {
    // weight transpose: wT[d*COUT+co] = weight[co*D+d], coalesced reads
    for (int i = (g - NB_BINS) * 256 + t; i < D * COUT; i += NB_WT * 256) {
      int co = i / D, d = i - co * D;
      wT[d * COUT + co] = weight[i];
    }
    return;
  }

  const int n = g / NBAND;
  const int band = g - n * NBAND;
  const int r0 = band * RB;

  for (int i = t; i < MEM; i += 256) lfirst[i] = P;   // local sentinel

  // channel sums for rows r0-1 .. r0+RB (zero for out-of-image rows).
  // float4 over pixels; per-pixel accumulation stays sequential c=0..63 (f64).
  const float* fb = fmap + (size_t)n * CIN * P;
  for (int u = t; u < HALO_F4; u += 256) {
    int lr = u / (W / 4);              // halo row 0..9
    int wu = u - lr * (W / 4);         // float4 index in row
    int gh = r0 - 1 + lr;
    double s0 = 0.0, s1 = 0.0, s2 = 0.0, s3 = 0.0;
    if (gh >= 0 && gh < H) {
      const float* pp = fb + gh * W + wu * 4;
      #pragma unroll
      for (int c = 0; c < CIN; ++c) {
        float4 v = *reinterpret_cast<const float4*>(pp + (size_t)c * P);
        s0 += (double)v.x; s1 += (double)v.y; s2 += (double)v.z; s3 += (double)v.w;
      }
    }
    double* dst = &Tl[lr * W + wu * 4];
    dst[0] = s0; dst[1] = s1; dst[2] = s2; dst[3] = s3;
  }
  __syncthreads();

  // 3x3 box sum -> replicate reference f32 ops -> bin -> LDS dedup
  for (int k = t; k < OUT_PIX; k += 256) {
    int orow = k / W, w = k - orow * W;
    double s = 0.0;
    #pragma unroll
    for (int dh = 0; dh < 3; ++dh) {
      const double* row = &Tl[(orow + dh) * W];
      #pragma unroll
      for (int dw = -1; dw <= 1; ++dw) {
        int ww = w + dw;
        if (ww < 0 || ww >= W) continue;
        s += row[ww];
      }
    }
    float sf = (float)s;
    float mean = sf / 576.0f;
    float v = mean * 100.0f;
    int qv = (int)v;                    // trunc toward zero == astype(int32)
    int b = qv + 512;                   // - MIN_SUMMARY
    b = b < 0 ? 0 : (b > MEM - 1 ? MEM - 1 : b);
    int p = (r0 + orow) * W + w;
    bins[n * P + p] = b;
    atomicMin(&lfirst[b], p);           // LDS-scope only
  }
  __syncthreads();

  // dense flush: init-free (sentinel entries written too), coalesced
  int* dst = first_band + ((size_t)n * NBAND + band) * MEM;
  for (int i = t; i < MEM; i += 256) dst[i] = lfirst[i];
}

// ---------------------------------------------------------------------------
// K2: representative GEMM per live (n, bin) pair.
//     first-occurrence = min over the image's 14 band winners (uniform loads).
__global__ __launch_bounds__(256) void rep_kernel(
    const float* __restrict__ fmap, const float* __restrict__ wT,
    const float* __restrict__ bias, const int* __restrict__ first_band,
    float* __restrict__ rep) {
  const int pair = blockIdx.x;          // n*MEM + b
  const int n = pair / MEM;
  const int b = pair - n * MEM;
  const int* fbp = first_band + (size_t)n * NBAND * MEM + b;
  int fi = P;
  #pragma unroll
  for (int band = 0; band < NBAND; ++band) {
    int v = fbp[(size_t)band * MEM];
    fi = v < fi ? v : fi;
  }
  if (fi >= P) return;                  // no patch maps to this bin
  __shared__ float patch[D];
  __shared__ float partial[4][COUT];
  const int t = threadIdx.x;
  int h = fi / W, w = fi - h * W;
  // gather patch: d = c*9 + kh*3 + kw (conv_general_dilated_patches order)
  for (int d = t; d < D; d += 256) {
    int c = d / 9, r = d - c * 9;
    int kh = r / 3, kw = r - kh * 3;
    int hh = h + kh - 1, ww = w + kw - 1;
    float val = 0.0f;
    if (hh >= 0 && hh < H && ww >= 0 && ww < W)
      val = fmap[((size_t)(n * CIN + c)) * P + hh * W + ww];
    patch[d] = val;
  }
  __syncthreads();
  int co = t & 63, seg = t >> 6;        // 4 segments x 144 d-values
  float acc = 0.0f;
  int d0 = seg * 144;
  #pragma unroll 4
  for (int d = d0; d < d0 + 144; ++d)
    acc += patch[d] * wT[d * COUT + co];
  partial[seg][co] = acc;
  __syncthreads();
  if (t < COUT) {
    float total = partial[0][t] + partial[1][t] + partial[2][t] + partial[3][t] + bias[t];
    rep[((size_t)pair) * COUT + t] = total;
  }
}

// ---------------------------------------------------------------------------
// K3: scatter out[n,co,p] = rep[n, bins[n,p], co], float4 writes
__global__ __launch_bounds__(256) void scatter_kernel(
    const int* __restrict__ bins, const float* __restrict__ rep,
    float* __restrict__ out) {
  int idx = blockIdx.x * 256 + threadIdx.x;          // over N*COUT*PG
  if (idx >= N_IMG * COUT * PG) return;
  int pv = idx % PG;
  int rest = idx / PG;
  int co = rest & 63;
  int n = rest >> 6;
  int4 b4 = *reinterpret_cast<const int4*>(bins + n * P + pv * 4);
  const float* repn = rep + (size_t)n * MEM * COUT + co;
  float4 o;
  o.x = repn[(size_t)b4.x * COUT];
  o.y = repn[(size_t)b4.y * COUT];
  o.z = repn[(size_t)b4.z * COUT];
  o.w = repn[(size_t)b4.w * COUT];
  *reinterpret_cast<float4*>(out + ((size_t)n * COUT + co) * P + pv * 4) = o;
}

// ---------------------------------------------------------------------------
extern "C" void kernel_launch(void* const* d_in, const int* in_sizes, int n_in,
                              void* d_out, int out_size, void* d_ws, size_t ws_size,
                              hipStream_t stream) {
  const float* fmap   = (const float*)d_in[0];
  const float* weight = (const float*)d_in[1];
  const float* bias   = (const float*)d_in[2];
  float* out = (float*)d_out;

  char* ws = (char*)d_ws;
  // workspace layout (all 64B-aligned)
  int*   bins       = (int*)  (ws);              // 8*12544*4      = 401408 B
  int*   first_band = (int*)  (ws + 401408);     // 8*14*1025*4    = 459200 B
  float* wT         = (float*)(ws + 860608);     // 576*64*4       = 147456 B
  float* rep        = (float*)(ws + 1008064);    // 8*1025*64*4    = 2099200 B

  hipLaunchKernelGGL(fused_bins_kernel, dim3(NB_BINS + NB_WT), dim3(256), 0, stream,
                     fmap, weight, wT, bins, first_band);
  hipLaunchKernelGGL(rep_kernel, dim3(N_IMG * MEM), dim3(256), 0, stream,
                     fmap, wT, bias, first_band, rep);
  hipLaunchKernelGGL(scatter_kernel, dim3((N_IMG * COUT * PG + 255) / 256), dim3(256), 0, stream,
                     bins, rep, out);
}